// Round 11
// baseline (11.666 us; speedup 1.0000x reference)
//
#include <hip/hip_runtime.h>
#include <hip/hip_bf16.h>
#include <math.h>

#define N_IN   128
#define N_OUT  128
#define BATCH  512
#define NB     11
#define FJ     12
#define KD     (N_IN * FJ)         // 1536
#define LSTR   1544                // bf16 row stride; 3088 B ≡ 16 B mod 128 (bank-spread)

typedef __attribute__((ext_vector_type(8))) short bf16x8;
typedef __attribute__((ext_vector_type(4))) float f32x4;

static __device__ __forceinline__ unsigned short bf1(float a) {
    __hip_bfloat16 h = __float2bfloat16(a);
    return *reinterpret_cast<unsigned short*>(&h);
}
static __device__ __forceinline__ unsigned pkbf(float a, float b) {
    return (unsigned)bf1(a) | ((unsigned)bf1(b) << 16);
}

// Fused KAN, TLP version: tile M=8 x N=16, 512 blocks x 512 thr,
// LDS 78.2 KB -> 2 blocks/CU (16 waves/CU, 4/SIMD) so two independent
// block pipelines overlap each other's load/barrier/MFMA stalls.
// MFMA A-operand rows 8-15 read garbage LDS (beyond Fl) -> masked at store.
__global__ __launch_bounds__(512, 4) void kan_fused6(
    const float* __restrict__ x, const float* __restrict__ grid,
    const float* __restrict__ c_basis, const float* __restrict__ c_res,
    const float* __restrict__ c_spl, float* __restrict__ out)
{
    __shared__ unsigned short Fl[8 * LSTR];    // 24.7 KB
    __shared__ unsigned short Wl[16 * LSTR];   // 49.4 KB
    __shared__ float part[8][128];             // 4 KB
    const int t   = threadIdx.x;
    const int bid = blockIdx.x;
    const int m0  = (bid >> 3) * 8;            // 64 m-groups
    const int n0  = (bid & 7) * 16;            // 8 XCD-pinned n-groups

    // ---- issue ALL global loads upfront ----
    float xr[2];
    #pragma unroll
    for (int r = 0; r < 2; ++r) {
        const int p = t + r * 512;             // 0..1023
        xr[r] = x[(m0 + (p >> 7)) * N_IN + (p & 127)];
    }
    float cb[4][NB], spl[4], res[4];
    #pragma unroll
    for (int r = 0; r < 4; ++r) {
        const size_t e = (size_t)n0 * N_IN + t + 512 * r;   // lane-local W row
        const float* cp = c_basis + e * NB;
        #pragma unroll
        for (int j = 0; j < NB; ++j) cb[r][j] = cp[j];
        spl[r] = c_spl[e];
        res[r] = c_res[e];
    }

    // ---- F build: 2 evals/thread ----
    const float lo = grid[3];
    const float hr = 1.0f / (grid[4] - grid[3]);
    #pragma unroll
    for (int r = 0; r < 2; ++r) {
        const int p  = t + r * 512;
        const int bl = p >> 7;                 // 0..7
        const int i  = p & 127;
        const float xv = xr[r];
        const float s  = (xv - lo) * hr;       // in [0,8)
        int c = (int)s; c = c < 0 ? 0 : (c > 7 ? 7 : c);
        const float u  = s - (float)c;
        const float um = 1.0f - u;
        const float u2 = u * u, u3 = u2 * u;
        const float B0 = um * um * um * (1.0f / 6.0f);
        const float B1 = (3.0f * u3 - 6.0f * u2 + 4.0f) * (1.0f / 6.0f);
        const float B2 = (-3.0f * u3 + 3.0f * u2 + 3.0f * u + 1.0f) * (1.0f / 6.0f);
        const float B3 = u3 * (1.0f / 6.0f);
        float fv[12];
        #pragma unroll
        for (int j = 0; j < NB; ++j) {
            const int d = j - c;
            fv[j] = (d == 0) ? B0 : (d == 1) ? B1 : (d == 2) ? B2 : (d == 3) ? B3 : 0.0f;
        }
        fv[11] = xv / (1.0f + __expf(-xv));    // silu
        uint2* dst = (uint2*)&Fl[bl * LSTR + i * FJ];
        dst[0] = make_uint2(pkbf(fv[0], fv[1]), pkbf(fv[2],  fv[3]));
        dst[1] = make_uint2(pkbf(fv[4], fv[5]), pkbf(fv[6],  fv[7]));
        dst[2] = make_uint2(pkbf(fv[8], fv[9]), pkbf(fv[10], fv[11]));
    }

    // ---- W build: 4 lane-local rows/thread ----
    #pragma unroll
    for (int r = 0; r < 4; ++r) {
        const int ol = (t >> 7) + 4 * r;       // (t + 512r) >> 7, 0..15
        const int i  = t & 127;
        float wv[12];
        #pragma unroll
        for (int j = 0; j < NB; ++j) wv[j] = spl[r] * cb[r][j];
        wv[11] = res[r];
        uint2* dst = (uint2*)&Wl[ol * LSTR + i * FJ];
        dst[0] = make_uint2(pkbf(wv[0], wv[1]), pkbf(wv[2],  wv[3]));
        dst[1] = make_uint2(pkbf(wv[4], wv[5]), pkbf(wv[6],  wv[7]));
        dst[2] = make_uint2(pkbf(wv[8], wv[9]), pkbf(wv[10], wv[11]));
    }

    __syncthreads();   // single pre-MFMA barrier

    // ---- MFMA: 8 waves split K=1536 into 8x192 -> 6 MFMA each ----
    const int wv_  = t >> 6;
    const int lane = t & 63;
    const int row  = lane & 15;
    const int kq   = (lane >> 4) * 8;
    const int k0   = wv_ * (KD / 8);
    f32x4 acc = {0.f, 0.f, 0.f, 0.f};
    #pragma unroll
    for (int ks = 0; ks < 6; ++ks) {
        const int k = k0 + ks * 32 + kq;
        const bf16x8 a = *(const bf16x8*)&Fl[row * LSTR + k];   // rows 8-15: garbage, masked below
        const bf16x8 b = *(const bf16x8*)&Wl[row * LSTR + k];
        acc = __builtin_amdgcn_mfma_f32_16x16x32_bf16(a, b, acc, 0, 0, 0);
    }

    // C/D layout (m89): col = lane&15, row = (lane>>4)*4 + r ; keep rows < 8
    #pragma unroll
    for (int r = 0; r < 4; ++r) {
        const int rr = (lane >> 4) * 4 + r;
        if (rr < 8) part[wv_][rr * 16 + (lane & 15)] = acc[r];
    }
    __syncthreads();

    if (t < 128) {
        float s = part[0][t] + part[1][t] + part[2][t] + part[3][t]
                + part[4][t] + part[5][t] + part[6][t] + part[7][t];
        out[(m0 + (t >> 4)) * N_OUT + n0 + (t & 15)] = s;
    }
}

extern "C" void kernel_launch(void* const* d_in, const int* in_sizes, int n_in,
                              void* d_out, int out_size, void* d_ws, size_t ws_size,
                              hipStream_t stream) {
    const float* x       = (const float*)d_in[0];
    const float* grid    = (const float*)d_in[1];
    const float* c_basis = (const float*)d_in[2];
    const float* c_res   = (const float*)d_in[3];
    const float* c_spl   = (const float*)d_in[4];
    float* out = (float*)d_out;

    kan_fused6<<<512, 512, 0, stream>>>(x, grid, c_basis, c_res, c_spl, out);
}

// Round 12
// 11.410 us; speedup vs baseline: 1.0224x; 1.0224x over previous
//
#include <hip/hip_runtime.h>
#include <hip/hip_bf16.h>
#include <math.h>

#define N_IN   128
#define N_OUT  128
#define BATCH  512
#define NB     11
#define FJ     12
#define KD     (N_IN * FJ)         // 1536
#define LSTR   1544                // bf16 row stride; 3088 B ≡ 16 B mod 128 (bank-spread)

typedef __attribute__((ext_vector_type(8))) short bf16x8;
typedef __attribute__((ext_vector_type(4))) float f32x4;

static __device__ __forceinline__ unsigned short bf1(float a) {
    __hip_bfloat16 h = __float2bfloat16(a);
    return *reinterpret_cast<unsigned short*>(&h);
}
static __device__ __forceinline__ unsigned pkbf(float a, float b) {
    return (unsigned)bf1(a) | ((unsigned)bf1(b) << 16);
}

// Fused KAN, minimal-critical-path version (best measured: 11.42 us):
//  - thread t owns W edges e = t + 512r  -> spl/res/c_basis lane-local in regs
//    (no Spl LDS staging, no magic div, no pre-MFMA barrier #1)
//  - all global loads issued upfront; F and W built independently; ONE barrier
//  - LDS writes as uint2 (ds_write_b64); MFMA fragment reads 2-way alias (free)
//  - 256 blocks = 1/CU; XCD-pinned n-groups (bid&7)
__global__ __launch_bounds__(512) void kan_fused5(
    const float* __restrict__ x, const float* __restrict__ grid,
    const float* __restrict__ c_basis, const float* __restrict__ c_res,
    const float* __restrict__ c_spl, float* __restrict__ out)
{
    __shared__ unsigned short Fl[16 * LSTR];   // 49.4 KB
    __shared__ unsigned short Wl[16 * LSTR];   // 49.4 KB
    __shared__ float part[8][256];             // 8 KB
    const int t   = threadIdx.x;
    const int bid = blockIdx.x;
    const int m0  = (bid >> 3) * 16;           // batch rows   (32 groups)
    const int n0  = (bid & 7) * 16;            // output cols  (8 XCD-pinned groups)

    // ---- issue ALL global loads upfront (independent -> deep ILP) ----
    float xr[4];
    #pragma unroll
    for (int r = 0; r < 4; ++r) {
        const int p = t + r * 512;
        xr[r] = x[(m0 + (p >> 7)) * N_IN + (p & 127)];
    }
    float cb[4][NB], spl[4], res[4];
    #pragma unroll
    for (int r = 0; r < 4; ++r) {
        const size_t e = (size_t)n0 * N_IN + t + 512 * r;
        const float* cp = c_basis + e * NB;
        #pragma unroll
        for (int j = 0; j < NB; ++j) cb[r][j] = cp[j];
        spl[r] = c_spl[e];
        res[r] = c_res[e];
    }

    // ---- F build: 4 evals/thread, 12 bf16 packed -> 3 ds_write_b64 ----
    const float lo = grid[3];
    const float hr = 1.0f / (grid[4] - grid[3]);
    #pragma unroll
    for (int r = 0; r < 4; ++r) {
        const int p  = t + r * 512;
        const int bl = p >> 7;
        const int i  = p & 127;
        const float xv = xr[r];
        const float s  = (xv - lo) * hr;       // in [0,8)
        int c = (int)s; c = c < 0 ? 0 : (c > 7 ? 7 : c);
        const float u  = s - (float)c;
        const float um = 1.0f - u;
        const float u2 = u * u, u3 = u2 * u;
        const float B0 = um * um * um * (1.0f / 6.0f);
        const float B1 = (3.0f * u3 - 6.0f * u2 + 4.0f) * (1.0f / 6.0f);
        const float B2 = (-3.0f * u3 + 3.0f * u2 + 3.0f * u + 1.0f) * (1.0f / 6.0f);
        const float B3 = u3 * (1.0f / 6.0f);
        float fv[12];
        #pragma unroll
        for (int j = 0; j < NB; ++j) {
            const int d = j - c;
            fv[j] = (d == 0) ? B0 : (d == 1) ? B1 : (d == 2) ? B2 : (d == 3) ? B3 : 0.0f;
        }
        fv[11] = xv / (1.0f + __expf(-xv));    // silu
        uint2* dst = (uint2*)&Fl[bl * LSTR + i * FJ];   // 8B-aligned (24i, 3088bl)
        dst[0] = make_uint2(pkbf(fv[0], fv[1]), pkbf(fv[2],  fv[3]));
        dst[1] = make_uint2(pkbf(fv[4], fv[5]), pkbf(fv[6],  fv[7]));
        dst[2] = make_uint2(pkbf(fv[8], fv[9]), pkbf(fv[10], fv[11]));
    }

    // ---- W build: lane-local rows, no barrier needed before this ----
    #pragma unroll
    for (int r = 0; r < 4; ++r) {
        const int ol = (t >> 7) + 4 * r;       // (t + 512r) >> 7
        const int i  = t & 127;
        float wv[12];
        #pragma unroll
        for (int j = 0; j < NB; ++j) wv[j] = spl[r] * cb[r][j];
        wv[11] = res[r];
        uint2* dst = (uint2*)&Wl[ol * LSTR + i * FJ];
        dst[0] = make_uint2(pkbf(wv[0], wv[1]), pkbf(wv[2],  wv[3]));
        dst[1] = make_uint2(pkbf(wv[4], wv[5]), pkbf(wv[6],  wv[7]));
        dst[2] = make_uint2(pkbf(wv[8], wv[9]), pkbf(wv[10], wv[11]));
    }

    __syncthreads();   // single pre-MFMA barrier

    // ---- MFMA: 8 waves split K=1536 into 8x192 -> 6 MFMA each ----
    const int wv_  = t >> 6;
    const int lane = t & 63;
    const int row  = lane & 15;
    const int kq   = (lane >> 4) * 8;
    const int k0   = wv_ * (KD / 8);
    f32x4 acc = {0.f, 0.f, 0.f, 0.f};
    #pragma unroll
    for (int ks = 0; ks < 6; ++ks) {
        const int k = k0 + ks * 32 + kq;
        const bf16x8 a = *(const bf16x8*)&Fl[row * LSTR + k];
        const bf16x8 b = *(const bf16x8*)&Wl[row * LSTR + k];
        acc = __builtin_amdgcn_mfma_f32_16x16x32_bf16(a, b, acc, 0, 0, 0);
    }

    // C/D layout (m89): col = lane&15, row = (lane>>4)*4 + r
    #pragma unroll
    for (int r = 0; r < 4; ++r)
        part[wv_][((lane >> 4) * 4 + r) * 16 + (lane & 15)] = acc[r];
    __syncthreads();

    if (t < 256) {
        float s = part[0][t] + part[1][t] + part[2][t] + part[3][t]
                + part[4][t] + part[5][t] + part[6][t] + part[7][t];
        out[(m0 + (t >> 4)) * N_OUT + n0 + (t & 15)] = s;
    }
}

extern "C" void kernel_launch(void* const* d_in, const int* in_sizes, int n_in,
                              void* d_out, int out_size, void* d_ws, size_t ws_size,
                              hipStream_t stream) {
    const float* x       = (const float*)d_in[0];
    const float* grid    = (const float*)d_in[1];
    const float* c_basis = (const float*)d_in[2];
    const float* c_res   = (const float*)d_in[3];
    const float* c_spl   = (const float*)d_in[4];
    float* out = (float*)d_out;

    kan_fused5<<<256, 512, 0, stream>>>(x, grid, c_basis, c_res, c_spl, out);
}